// Round 15
// baseline (267.503 us; speedup 1.0000x reference)
//
#include <hip/hip_runtime.h>
#include <stdint.h>

#define NROWS 65536
#define HD 1024

typedef __attribute__((ext_vector_type(8))) short bf16x8;   // 8 bf16 in 4 VGPRs
typedef __attribute__((ext_vector_type(16))) float f32x16;  // MFMA 32x32 accumulator

typedef __attribute__((address_space(1))) const unsigned int* gas_ptr;
typedef __attribute__((address_space(3))) unsigned int* las_ptr;

__device__ __forceinline__ unsigned short f2bf(float f) {
  union { float f; uint32_t u; } v; v.f = f;
  uint32_t u = v.u;
  return (unsigned short)((u + 0x7fffu + ((u >> 16) & 1u)) >> 16);  // RNE
}

__device__ __forceinline__ void gl16(const void* g, void* l) {
  __builtin_amdgcn_global_load_lds((gas_ptr)g, (las_ptr)l, 16, 0, 0);
}

// ---------------- prep: W2 fp32 -> bf16 packed in MFMA-fragment order, 64-col ct tiles ----------------
// granule i: lane=i&63, f=(i>>6)&7 (f=cb*4+p*2+kl), T=(i>>9)&15, ct=i>>13 (16 cts).
// col = ct*64 + cb*32 + (lane&31); k = T*64 + p*32 + kl*16 + (lane>>5)*8.
__global__ void k_w2pk(const float* __restrict__ W2, unsigned short* __restrict__ W2pk) {
  int i = blockIdx.x * 256 + threadIdx.x;   // 131072 granules
  int lane = i & 63, f = (i >> 6) & 7, T = (i >> 9) & 15, ct = i >> 13;
  int kl = f & 1, p = (f >> 1) & 1, cb = f >> 2;
  int col = ct * 64 + cb * 32 + (lane & 31);
  int k = T * 64 + p * 32 + kl * 16 + (lane >> 5) * 8;
  const float4* s4 = (const float4*)(W2 + (size_t)col * HD + k);
  float4 a = s4[0], b = s4[1];
  uint4 pk;
  pk.x = (uint32_t)f2bf(a.x) | ((uint32_t)f2bf(a.y) << 16);
  pk.y = (uint32_t)f2bf(a.z) | ((uint32_t)f2bf(a.w) << 16);
  pk.z = (uint32_t)f2bf(b.x) | ((uint32_t)f2bf(b.y) << 16);
  pk.w = (uint32_t)f2bf(b.z) | ((uint32_t)f2bf(b.w) << 16);
  *(uint4*)(W2pk + (size_t)i * 8) = pk;
}

// ---------------- layer 1: h bf16 [65536][1024], 8-granule swizzle (g&7)^(row&7) ----------------
__global__ __launch_bounds__(512) void k_layer1(
    const float* __restrict__ x, const float* __restrict__ W1,
    const float* __restrict__ b1, const float* __restrict__ Wmeta,
    const float* __restrict__ bmeta, unsigned short* __restrict__ h) {
  __shared__ float xs[64 * 12];
  int r0 = blockIdx.x * 64;
  int t = threadIdx.x;
  int j0 = t * 2;
  float w1a = W1[j0], w1b = W1[j0 + 1];
  float b1a = b1[j0], b1b = b1[j0 + 1];
  float wma[10], wmb[10], bma[10], bmb[10];
#pragma unroll
  for (int e = 0; e < 10; e++) {
    float2 wmv = *(const float2*)(Wmeta + e * HD + j0);
    float2 bmv = *(const float2*)(bmeta + e * HD + j0);
    wma[e] = wmv.x; wmb[e] = wmv.y; bma[e] = bmv.x; bmb[e] = bmv.y;
  }
  for (int i = t; i < 64 * 12; i += 512) xs[i] = x[(size_t)r0 * 12 + i];
  __syncthreads();
  int g = j0 >> 3;
  for (int r = 0; r < 64; r++) {
    const float* xr = xs + r * 12;
    float delta = xr[10], phi = xr[11];
    float s1a = 0.f, s1b = 0.f, s2a = 0.f, s2b = 0.f;
#pragma unroll
    for (int e = 0; e < 10; e++) {
      float oh = xr[e];
      s1a = fmaf(oh, wma[e], s1a);
      s1b = fmaf(oh, wmb[e], s1b);
      s2a = fmaf(oh, bma[e], s2a);
      s2b = fmaf(oh, bmb[e], s2b);
    }
    float pa = fmaf(delta, w1a, b1a) + fmaf(phi, s1a, s2a);
    float pb = fmaf(delta, w1b, b1b) + fmaf(phi, s1b, s2b);
    pa = fmaxf(pa, 0.f); pb = fmaxf(pb, 0.f);
    uint32_t pk = (uint32_t)f2bf(pa) | ((uint32_t)f2bf(pb) << 16);
    int rr = r0 + r;
    int gs = (g & 120) | ((g & 7) ^ (rr & 7));
    *(uint32_t*)(h + (size_t)rr * HD + gs * 8 + (j0 & 7)) = pk;
  }
}

// ---------------- layers 2+3: barrier-free wave-private pipeline ----------------
// grid 4096 (XCD-swizzled) = 256 rowblocks(256 rows) x 16 ct(64 cols); 256 threads =
// 4 waves, each owning a PRIVATE 64-row band + private 16KB LDS double-buffer.
// ZERO barriers: all ordering is wave-local s_waitcnt. Per K-tile (unrolled):
//   {8 gl16: A(T+1)->buf^1 | 8 global_load: B(T+1)->regs | vmcnt(16): A(T),B(T)
//    landed (issued a full iter ago), newest 16 stay in flight | 8 ds_read A(T) |
//    lgkmcnt(0) | 16 MFMA with B(T) regs}.
// LDS WAR is wave-local: ds_reads(T) retire (lgkm0) before stage(T+2) issues in
// program order. B from fragment-packed L2-resident W2pk (R13-proven).
__global__ __launch_bounds__(256, 2) void k_gemm(
    const unsigned short* __restrict__ h, const unsigned short* __restrict__ W2pk,
    const float* __restrict__ b2, const float* __restrict__ W3,
    float* __restrict__ partial) {
  __shared__ char lds[65536];   // 4 waves x (2 bufs x 8 KB)
  int tid = threadIdx.x;
  // XCD swizzle: 4096 blocks = 8 XCDs x 512; 16 consecutive bx share a row panel.
  int b = (int)blockIdx.x;
  int bx = ((b & 7) << 9) | (b >> 3);
  int rblk = bx >> 4, ct = bx & 15;
  size_t r0 = (size_t)rblk * 256;
  int c0 = ct * 64;
  int w = tid >> 6, lane = tid & 63;
  int l31 = lane & 31, hi = lane >> 5;
  char* ldsw = lds + w * 16384;   // wave-private region

  f32x16 acc[2][2];
#pragma unroll
  for (int rb = 0; rb < 2; rb++)
#pragma unroll
    for (int cb = 0; cb < 2; cb++)
#pragma unroll
      for (int i = 0; i < 16; i++) acc[rb][cb][i] = 0.f;

  // A staging source: wave w's rows r0+w*64 .. +63; lane covers row (lane>>3), granule lane&7.
  const unsigned short* aSrc = h + (r0 + w * 64 + (lane >> 3)) * (size_t)HD + (lane & 7) * 8;
  // B source: per-lane base; frag f of tile T at +(T*512 + f*64)*8 elems.
  const unsigned short* bSrc = W2pk + ((size_t)ct * 8192 + lane) * 8;

  // stage A(T) into buf: 8 gl16, dest = wave base + buf*8192 + q*1024 + lane*16 (lane-linear)
#define STAGE_A(T, BUF)                                                           \
  do {                                                                            \
    _Pragma("unroll")                                                             \
    for (int q = 0; q < 8; q++)                                                   \
      gl16(aSrc + (size_t)q * 8 * HD + (T) * 64,                                  \
           ldsw + (BUF) * 8192 + q * 1024 + (lane & 63) * 16);                    \
  } while (0)

  bf16x8 B[2][8];
  // prologue: A(0)->buf0, B(0)->B[0]
  STAGE_A(0, 0);
#pragma unroll
  for (int f = 0; f < 8; f++) B[0][f] = *(const bf16x8*)(bSrc + (0 * 512 + f * 64) * 8);

  int slotBase = l31 & 7;   // row&7 (rows r and r+32 share &7)
#pragma unroll
  for (int T = 0; T < 16; T++) {
    const int cur = T & 1, nxt = cur ^ 1;
    if (T < 15) {
      STAGE_A(T + 1, nxt);
#pragma unroll
      for (int f = 0; f < 8; f++)
        B[nxt][f] = *(const bf16x8*)(bSrc + ((T + 1) * 512 + f * 64) * 8);
    }
    // A(T),B(T) issued a full iteration ago -> landed once newest 16 remain
    if (T < 15) { asm volatile("s_waitcnt vmcnt(16)" ::: "memory"); }
    else        { asm volatile("s_waitcnt vmcnt(0)" ::: "memory"); }
    __builtin_amdgcn_sched_barrier(0);
    // 8 ds_read_b128: A fragments of tile T (rows l31 / l31+32, k-granule s*2+hi)
    bf16x8 a0[4], a1[4];
#pragma unroll
    for (int s = 0; s < 4; s++) {
      int sl = ((s * 2 + hi) ^ slotBase) << 4;
      a0[s] = *(const bf16x8*)(ldsw + cur * 8192 + l31 * 128 + sl);
      a1[s] = *(const bf16x8*)(ldsw + cur * 8192 + (l31 + 32) * 128 + sl);
    }
    asm volatile("s_waitcnt lgkmcnt(0)" ::: "memory");
    __builtin_amdgcn_sched_barrier(0);
    __builtin_amdgcn_s_setprio(1);
#pragma unroll
    for (int s = 0; s < 4; s++) {
      acc[0][0] = __builtin_amdgcn_mfma_f32_32x32x16_bf16(a0[s], B[cur][s],     acc[0][0], 0, 0, 0);
      acc[0][1] = __builtin_amdgcn_mfma_f32_32x32x16_bf16(a0[s], B[cur][4 + s], acc[0][1], 0, 0, 0);
      acc[1][0] = __builtin_amdgcn_mfma_f32_32x32x16_bf16(a1[s], B[cur][s],     acc[1][0], 0, 0, 0);
      acc[1][1] = __builtin_amdgcn_mfma_f32_32x32x16_bf16(a1[s], B[cur][4 + s], acc[1][1], 0, 0, 0);
    }
    __builtin_amdgcn_s_setprio(0);
  }

  // ---- epilogue: pure in-wave (wave owns rows x full block cols) — no LDS, no syncs ----
  float b2c[2], w30[2], w31[2];
#pragma unroll
  for (int cb = 0; cb < 2; cb++) {
    int c = c0 + cb * 32 + l31;
    b2c[cb] = b2[c];
    w30[cb] = W3[c];
    w31[cb] = W3[HD + c];
  }
#pragma unroll
  for (int rb = 0; rb < 2; rb++) {
#pragma unroll
    for (int reg = 0; reg < 16; reg++) {
      float v0 = fmaxf(acc[rb][0][reg] + b2c[0], 0.f);
      float v1 = fmaxf(acc[rb][1][reg] + b2c[1], 0.f);
      float o0 = fmaf(v0, w30[0], v1 * w30[1]);
      float o1 = fmaf(v0, w31[0], v1 * w31[1]);
#pragma unroll
      for (int m = 16; m >= 1; m >>= 1) {  // reduce over cols (l31); stays in 32-lane half
        o0 += __shfl_xor(o0, m);
        o1 += __shfl_xor(o1, m);
      }
      if (l31 == 0) {
        size_t row = r0 + w * 64 + rb * 32 + (reg & 3) + 8 * (reg >> 2) + 4 * hi;  // C/D map
        float2 o; o.x = o0; o.y = o1;
        *(float2*)(partial + (size_t)ct * (NROWS * 2) + row * 2) = o;
      }
    }
  }
}

// ---------------- final: out = b3 + sum over 16 col-tile partials ----------------
__global__ void k_reduce(const float* __restrict__ partial, const float* __restrict__ b3,
                         float* __restrict__ out) {
  int i = blockIdx.x * 256 + threadIdx.x;  // 131072
  float s = b3[i & 1];
#pragma unroll
  for (int ctt = 0; ctt < 16; ctt++) s += partial[(size_t)ctt * 131072 + i];
  out[i] = s;
}

extern "C" void kernel_launch(void* const* d_in, const int* in_sizes, int n_in,
                              void* d_out, int out_size, void* d_ws, size_t ws_size,
                              hipStream_t stream) {
  const float* x     = (const float*)d_in[0];
  const float* W1    = (const float*)d_in[1];
  const float* b1    = (const float*)d_in[2];
  const float* Wmeta = (const float*)d_in[3];
  const float* bmeta = (const float*)d_in[4];
  const float* W2    = (const float*)d_in[5];
  const float* b2    = (const float*)d_in[6];
  const float* W3    = (const float*)d_in[7];
  const float* b3    = (const float*)d_in[8];
  float* out = (float*)d_out;

  char* ws = (char*)d_ws;
  unsigned short* hbuf  = (unsigned short*)ws;                              // 128 MiB
  unsigned short* W2pk  = (unsigned short*)(ws + (size_t)NROWS * HD * 2);   // 2 MiB
  float* partial = (float*)(ws + (size_t)NROWS * HD * 2 + (size_t)HD * HD * 2);  // 8 MiB (16 slices)

  k_w2pk<<<512, 256, 0, stream>>>(W2, W2pk);
  k_layer1<<<1024, 512, 0, stream>>>(x, W1, b1, Wmeta, bmeta, hbuf);
  k_gemm<<<4096, 256, 0, stream>>>(hbuf, W2pk, b2, W3, partial);
  k_reduce<<<512, 256, 0, stream>>>(partial, b3, out);
}

// Round 16
// 214.487 us; speedup vs baseline: 1.2472x; 1.2472x over previous
//
#include <hip/hip_runtime.h>
#include <stdint.h>

#define NROWS 65536
#define HD 1024

typedef __attribute__((ext_vector_type(8))) short bf16x8;   // 8 bf16 in 4 VGPRs
typedef __attribute__((ext_vector_type(16))) float f32x16;  // MFMA 32x32 accumulator

typedef __attribute__((address_space(1))) const unsigned int* gas_ptr;
typedef __attribute__((address_space(3))) unsigned int* las_ptr;

__device__ __forceinline__ unsigned short f2bf(float f) {
  union { float f; uint32_t u; } v; v.f = f;
  uint32_t u = v.u;
  return (unsigned short)((u + 0x7fffu + ((u >> 16) & 1u)) >> 16);  // RNE
}

__device__ __forceinline__ void gl16(const void* g, void* l) {
  __builtin_amdgcn_global_load_lds((gas_ptr)g, (las_ptr)l, 16, 0, 0);
}

// ---------------- merged prep: blocks 0-255 pack W2, blocks 256-1279 compute layer 1 ----------------
// W2pk (R13 layout): granule i: lane=i&63, f=(i>>6)&15 (f=wn*8+cb*4+p*2+kl), T=(i>>10)&15, ct=i>>14.
// col = ct*128+wn*64+cb*32+(lane&31); k = T*64+p*32+kl*16+(lane>>5)*8.
// h (R13 layout): bf16 [65536][1024], granule swizzle (g&3)^((row>>1)&3).
__global__ __launch_bounds__(512) void k_prep(
    const float* __restrict__ x, const float* __restrict__ W1,
    const float* __restrict__ b1, const float* __restrict__ Wmeta,
    const float* __restrict__ bmeta, const float* __restrict__ W2,
    unsigned short* __restrict__ h, unsigned short* __restrict__ W2pk) {
  __shared__ float xs[64 * 12];
  if (blockIdx.x < 256) {   // ---- W2 fragment packing: 131072 granules ----
    int i = blockIdx.x * 512 + threadIdx.x;
    int lane = i & 63, f = (i >> 6) & 15, T = (i >> 10) & 15, ct = i >> 14;
    int kl = f & 1, p = (f >> 1) & 1, cb = (f >> 2) & 1, wn = f >> 3;
    int col = ct * 128 + wn * 64 + cb * 32 + (lane & 31);
    int k = T * 64 + p * 32 + kl * 16 + (lane >> 5) * 8;
    const float4* s4 = (const float4*)(W2 + (size_t)col * HD + k);
    float4 a = s4[0], b = s4[1];
    uint4 pk;
    pk.x = (uint32_t)f2bf(a.x) | ((uint32_t)f2bf(a.y) << 16);
    pk.y = (uint32_t)f2bf(a.z) | ((uint32_t)f2bf(a.w) << 16);
    pk.z = (uint32_t)f2bf(b.x) | ((uint32_t)f2bf(b.y) << 16);
    pk.w = (uint32_t)f2bf(b.z) | ((uint32_t)f2bf(b.w) << 16);
    *(uint4*)(W2pk + (size_t)i * 8) = pk;
    return;
  }
  // ---- layer 1: h = relu(delta*W1 + b1 + phi*(oh@Wmeta) + oh@bmeta), 64 rows/block ----
  int r0 = ((int)blockIdx.x - 256) * 64;
  int t = threadIdx.x;
  int j0 = t * 2;
  float w1a = W1[j0], w1b = W1[j0 + 1];
  float b1a = b1[j0], b1b = b1[j0 + 1];
  float wma[10], wmb[10], bma[10], bmb[10];
#pragma unroll
  for (int e = 0; e < 10; e++) {
    float2 wmv = *(const float2*)(Wmeta + e * HD + j0);
    float2 bmv = *(const float2*)(bmeta + e * HD + j0);
    wma[e] = wmv.x; wmb[e] = wmv.y; bma[e] = bmv.x; bmb[e] = bmv.y;
  }
  for (int i = t; i < 64 * 12; i += 512) xs[i] = x[(size_t)r0 * 12 + i];
  __syncthreads();
  int g = j0 >> 3;
  for (int r = 0; r < 64; r++) {
    const float* xr = xs + r * 12;
    float delta = xr[10], phi = xr[11];
    float s1a = 0.f, s1b = 0.f, s2a = 0.f, s2b = 0.f;
#pragma unroll
    for (int e = 0; e < 10; e++) {
      float oh = xr[e];
      s1a = fmaf(oh, wma[e], s1a);
      s1b = fmaf(oh, wmb[e], s1b);
      s2a = fmaf(oh, bma[e], s2a);
      s2b = fmaf(oh, bmb[e], s2b);
    }
    float pa = fmaf(delta, w1a, b1a) + fmaf(phi, s1a, s2a);
    float pb = fmaf(delta, w1b, b1b) + fmaf(phi, s1b, s2b);
    pa = fmaxf(pa, 0.f); pb = fmaxf(pb, 0.f);
    uint32_t pk = (uint32_t)f2bf(pa) | ((uint32_t)f2bf(pb) << 16);
    int rr = r0 + r;
    int gs = (g & 124) | ((g & 3) ^ ((rr >> 1) & 3));
    *(uint32_t*)(h + (size_t)rr * HD + gs * 8 + (j0 & 7)) = pk;
  }
}

// ---------------- layers 2+3: 3-slot A rotation + B-in-regs + counted vmcnt @ 3 blocks/CU ----------------
// grid 4096 (XCD-swizzled) = 512 rt x 8 ct; 256 threads = 4 waves (2wm x 2wn), wave tile
// 64x64 = 2x2 of 32x32x16 bf16 MFMA (acc 64). LDS: 3 slots x 16 KB (A only) = 48 KB ->
// 3 blocks/CU. B register-direct from fragment-packed L2-resident W2pk (R13).
// Per tile T: {8 ds_read A(T) | stage A(T+2)->slot(T+2)%3 (4 gl16) | B(T+1) f0-3 (4 gld) |
//   vmcnt(8): iter T-1 fully retired -> A(T),B(T) ready, A(T+1) retired pre-barrier |
//   lgkm(0) | 8 MFMA cb0 | B(T+1) f4-7 | 8 MFMA cb1 | s_barrier}.
// ONE raw barrier/tile, vmcnt never 0 until the tail (8/4/0 at T<=13/14/15). Cross-wave
// staging visibility: each wave drains its OWN iter T-1 loads (vmcnt) before barrier(T).
// Slot WAR: stage(T+2) hits slot(T-1), whose reads retired (lgkm0) before barrier(T-1).
__global__ __launch_bounds__(256, 3) void k_gemm(
    const unsigned short* __restrict__ h, const unsigned short* __restrict__ W2pk,
    const float* __restrict__ b2, const float* __restrict__ W3,
    float* __restrict__ partial) {
  __shared__ char lds[49152];   // 3 x 16 KB A slots (panels @0/@8192); epilogue reuses 33792 B
  int tid = threadIdx.x;
  int b = (int)blockIdx.x;
  int bx = ((b & 7) << 9) | (b >> 3);   // XCD swizzle: 8 XCDs x 512
  int rt = bx >> 3, ct = bx & 7;        // 8 consecutive bx share rt -> A-panel L2 reuse
  size_t r0 = (size_t)rt * 128;
  int c0 = ct * 128;
  int w = tid >> 6, lane = tid & 63;
  int wm = w >> 1, wn = w & 1;
  int l31 = lane & 31, hi = lane >> 5;
  int sw = (l31 >> 1) & 3;              // A granule swizzle key
  int s0 = (hi ^ sw) << 4;              // kl=0 granule byte
  int s1 = ((2 + hi) ^ sw) << 4;        // kl=1 granule byte

  f32x16 acc[2][2];
#pragma unroll
  for (int rb = 0; rb < 2; rb++)
#pragma unroll
    for (int cb = 0; cb < 2; cb++)
#pragma unroll
      for (int i = 0; i < 16; i++) acc[rb][cb][i] = 0.f;

  int arow0 = (wm * 64 + 0  + l31) * 64;
  int arow1 = (wm * 64 + 32 + l31) * 64;
  const unsigned short* bwave = W2pk + ((size_t)ct * 256 + (size_t)wn * 8) * 512 + lane * 8;

  // stage A(T) into slot base SB: 4 gl16/thread, dest lane-linear, source pre-swizzled
#define STAGE_A(T, SB)                                                            \
  do {                                                                            \
    _Pragma("unroll")                                                             \
    for (int q = 0; q < 2; q++) {                                                 \
      int s = tid + 256 * q;                                                      \
      int row = s >> 2, g4 = s & 3;                                               \
      const unsigned short* hsrc = h + (r0 + row) * (size_t)HD + (T) * 64 + g4 * 8; \
      gl16(hsrc,      lds + (SB) +        (size_t)s * 16);                        \
      gl16(hsrc + 32, lds + (SB) + 8192 + (size_t)s * 16);                        \
    }                                                                             \
  } while (0)

#define GBODY(T, BC, BN)                                                          \
  do {                                                                            \
    const char* lA0 = lds + slotT;                                                \
    const char* lA1 = lds + slotT + 8192;                                         \
    bf16x8 a00 = *(const bf16x8*)(lA0 + arow0 + s0);  /* p0 kl0 rb0 */            \
    bf16x8 a01 = *(const bf16x8*)(lA0 + arow1 + s0);                              \
    bf16x8 a02 = *(const bf16x8*)(lA0 + arow0 + s1);  /* p0 kl1 */                \
    bf16x8 a03 = *(const bf16x8*)(lA0 + arow1 + s1);                              \
    bf16x8 a10 = *(const bf16x8*)(lA1 + arow0 + s0);  /* p1 kl0 */                \
    bf16x8 a11 = *(const bf16x8*)(lA1 + arow1 + s0);                              \
    bf16x8 a12 = *(const bf16x8*)(lA1 + arow0 + s1);  /* p1 kl1 */                \
    bf16x8 a13 = *(const bf16x8*)(lA1 + arow1 + s1);                              \
    if ((T) < 14) STAGE_A((T) + 2, slotS);                                        \
    const unsigned short* btn = bwave + (size_t)((T) + 1) * 8192;                 \
    if ((T) < 15) {                                                               \
      BN[0] = *(const bf16x8*)(btn + 0 * 512);                                    \
      BN[1] = *(const bf16x8*)(btn + 1 * 512);                                    \
      BN[2] = *(const bf16x8*)(btn + 2 * 512);                                    \
      BN[3] = *(const bf16x8*)(btn + 3 * 512);                                    \
    }                                                                             \
    if ((T) <= 13)      { asm volatile("s_waitcnt vmcnt(8)" ::: "memory"); }      \
    else if ((T) == 14) { asm volatile("s_waitcnt vmcnt(4)" ::: "memory"); }      \
    else                { asm volatile("s_waitcnt vmcnt(0)" ::: "memory"); }      \
    asm volatile("s_waitcnt lgkmcnt(0)" ::: "memory");                            \
    __builtin_amdgcn_sched_barrier(0);                                            \
    __builtin_amdgcn_s_setprio(1);                                                \
    acc[0][0] = __builtin_amdgcn_mfma_f32_32x32x16_bf16(a00, BC[0], acc[0][0], 0, 0, 0); \
    acc[1][0] = __builtin_amdgcn_mfma_f32_32x32x16_bf16(a01, BC[0], acc[1][0], 0, 0, 0); \
    acc[0][0] = __builtin_amdgcn_mfma_f32_32x32x16_bf16(a02, BC[1], acc[0][0], 0, 0, 0); \
    acc[1][0] = __builtin_amdgcn_mfma_f32_32x32x16_bf16(a03, BC[1], acc[1][0], 0, 0, 0); \
    acc[0][0] = __builtin_amdgcn_mfma_f32_32x32x16_bf16(a10, BC[2], acc[0][0], 0, 0, 0); \
    acc[1][0] = __builtin_amdgcn_mfma_f32_32x32x16_bf16(a11, BC[2], acc[1][0], 0, 0, 0); \
    acc[0][0] = __builtin_amdgcn_mfma_f32_32x32x16_bf16(a12, BC[3], acc[0][0], 0, 0, 0); \
    acc[1][0] = __builtin_amdgcn_mfma_f32_32x32x16_bf16(a13, BC[3], acc[1][0], 0, 0, 0); \
    __builtin_amdgcn_s_setprio(0);                                                \
    if ((T) < 15) {                                                               \
      BN[4] = *(const bf16x8*)(btn + 4 * 512);                                    \
      BN[5] = *(const bf16x8*)(btn + 5 * 512);                                    \
      BN[6] = *(const bf16x8*)(btn + 6 * 512);                                    \
      BN[7] = *(const bf16x8*)(btn + 7 * 512);                                    \
    }                                                                             \
    __builtin_amdgcn_s_setprio(1);                                                \
    acc[0][1] = __builtin_amdgcn_mfma_f32_32x32x16_bf16(a00, BC[4], acc[0][1], 0, 0, 0); \
    acc[1][1] = __builtin_amdgcn_mfma_f32_32x32x16_bf16(a01, BC[4], acc[1][1], 0, 0, 0); \
    acc[0][1] = __builtin_amdgcn_mfma_f32_32x32x16_bf16(a02, BC[5], acc[0][1], 0, 0, 0); \
    acc[1][1] = __builtin_amdgcn_mfma_f32_32x32x16_bf16(a03, BC[5], acc[1][1], 0, 0, 0); \
    acc[0][1] = __builtin_amdgcn_mfma_f32_32x32x16_bf16(a10, BC[6], acc[0][1], 0, 0, 0); \
    acc[1][1] = __builtin_amdgcn_mfma_f32_32x32x16_bf16(a11, BC[6], acc[1][1], 0, 0, 0); \
    acc[0][1] = __builtin_amdgcn_mfma_f32_32x32x16_bf16(a12, BC[7], acc[0][1], 0, 0, 0); \
    acc[1][1] = __builtin_amdgcn_mfma_f32_32x32x16_bf16(a13, BC[7], acc[1][1], 0, 0, 0); \
    __builtin_amdgcn_s_setprio(0);                                                \
    __builtin_amdgcn_s_barrier();                                                 \
    slotT += 16384; if (slotT == 49152) slotT = 0;                                \
    slotS += 16384; if (slotS == 49152) slotS = 0;                                \
  } while (0)

  bf16x8 B0s[8], B1s[8];
  // prologue: B(0) all 8 frags first, then A(0)->slot0, A(1)->slot1; wait B(0)+A(0).
  {
    const unsigned short* bt0 = bwave;
#pragma unroll
    for (int f = 0; f < 8; f++) B0s[f] = *(const bf16x8*)(bt0 + f * 512);
  }
  STAGE_A(0, 0);
  STAGE_A(1, 16384);
  asm volatile("s_waitcnt vmcnt(4)" ::: "memory");   // newest 4 (A(1)) may fly
  __builtin_amdgcn_s_barrier();

  int slotT = 0, slotS = 32768;   // read slot of tile T; staging slot of tile T+2
  for (int TT = 0; TT < 8; TT++) {
    GBODY(TT * 2,     B0s, B1s);
    GBODY(TT * 2 + 1, B1s, B0s);
  }
  __syncthreads();

  // ---- epilogue (R13 verbatim): v = relu(acc+b2); o = v x W3^T; LDS transpose-reduce ----
  float b2c[2], w30[2], w31[2];
#pragma unroll
  for (int cb = 0; cb < 2; cb++) {
    int c = c0 + wn * 64 + cb * 32 + l31;
    b2c[cb] = b2[c];
    w30[cb] = W3[c];
    w31[cb] = W3[HD + c];
  }
  float2* sE = (float2*)lds;   // 128 lines x 33 float2 = 33792 B
#pragma unroll
  for (int rb = 0; rb < 2; rb++) {
    __syncthreads();
#pragma unroll
    for (int reg = 0; reg < 16; reg++) {
      float v0 = fmaxf(acc[rb][0][reg] + b2c[0], 0.f);
      float v1 = fmaxf(acc[rb][1][reg] + b2c[1], 0.f);
      float2 o;
      o.x = v0 * w30[0] + v1 * w30[1];
      o.y = v0 * w31[0] + v1 * w31[1];
      int rowf = (reg & 3) + 8 * (reg >> 2) + 4 * hi;   // verified C/D row map
      int line = (wm * 32 + rowf) * 2 + wn;
      sE[line * 33 + l31] = o;
    }
    __syncthreads();
    int half = tid & 1, tgt = tid >> 1;
    int d = tgt & 1, rowf_t = (tgt >> 1) & 31, bi = tgt >> 6;
    int line0 = (bi * 32 + rowf_t) * 2 + half;
    const float* sf = (const float*)lds;
    float s = 0.f;
#pragma unroll
    for (int j = 0; j < 32; j++) s += sf[(line0 * 33 + j) * 2 + d];
    s += __shfl_xor(s, 1);
    if (half == 0) {
      int row = bi * 64 + rb * 32 + rowf_t;
      partial[(size_t)ct * (NROWS * 2) + (r0 + row) * 2 + d] = s;
    }
  }
}

// ---------------- final: out = b3 + sum over 8 col-tile partials ----------------
__global__ void k_reduce(const float* __restrict__ partial, const float* __restrict__ b3,
                         float* __restrict__ out) {
  int i = blockIdx.x * 256 + threadIdx.x;  // 131072
  float s = b3[i & 1];
#pragma unroll
  for (int ctt = 0; ctt < 8; ctt++) s += partial[(size_t)ctt * 131072 + i];
  out[i] = s;
}

extern "C" void kernel_launch(void* const* d_in, const int* in_sizes, int n_in,
                              void* d_out, int out_size, void* d_ws, size_t ws_size,
                              hipStream_t stream) {
  const float* x     = (const float*)d_in[0];
  const float* W1    = (const float*)d_in[1];
  const float* b1    = (const float*)d_in[2];
  const float* Wmeta = (const float*)d_in[3];
  const float* bmeta = (const float*)d_in[4];
  const float* W2    = (const float*)d_in[5];
  const float* b2    = (const float*)d_in[6];
  const float* W3    = (const float*)d_in[7];
  const float* b3    = (const float*)d_in[8];
  float* out = (float*)d_out;

  char* ws = (char*)d_ws;
  unsigned short* hbuf  = (unsigned short*)ws;                              // 128 MiB
  unsigned short* W2pk  = (unsigned short*)(ws + (size_t)NROWS * HD * 2);   // 2 MiB
  float* partial = (float*)(ws + (size_t)NROWS * HD * 2 + (size_t)HD * HD * 2);  // 4 MiB (8 slices)

  k_prep<<<1280, 512, 0, stream>>>(x, W1, b1, Wmeta, bmeta, W2, hbuf, W2pk);
  k_gemm<<<4096, 256, 0, stream>>>(hbuf, W2pk, b2, W3, partial);
  k_reduce<<<512, 256, 0, stream>>>(partial, b3, out);
}